// Round 1
// baseline (10.052 us; speedup 1.0000x reference)
//
#include <hip/hip_runtime.h>
#include <hip/hip_bf16.h>

// Embedding gather: out[r, :] = W[indices[r], :], r in [0, 8192), D=128 f32.
// Each 32-thread group handles one row; each thread moves one float4 (16 B).
// 256 threads/block -> 8 rows/block -> 1024 blocks total.

#define N_ROWS 8192   // 4 * 2048
#define DIM    128
#define F4_PER_ROW (DIM / 4)   // 32

__global__ __launch_bounds__(256) void embedding_gather_kernel(
    const int* __restrict__ indices,
    const float4* __restrict__ W4,
    float4* __restrict__ out4) {
  const int t = blockIdx.x * blockDim.x + threadIdx.x;       // global thread id
  const int row = t >> 5;                                    // t / 32
  const int lane = t & 31;                                   // t % 32
  if (row >= N_ROWS) return;
  const int idx = indices[row];
  out4[(size_t)row * F4_PER_ROW + lane] = W4[(size_t)idx * F4_PER_ROW + lane];
}

extern "C" void kernel_launch(void* const* d_in, const int* in_sizes, int n_in,
                              void* d_out, int out_size, void* d_ws, size_t ws_size,
                              hipStream_t stream) {
  const int* indices = (const int*)d_in[0];          // (4, 2048) int32
  const float4* W4   = (const float4*)d_in[1];       // (50257, 128) f32 as float4
  float4* out4       = (float4*)d_out;               // (4, 2048, 128) f32 as float4

  const int total_threads = N_ROWS * 32;             // 262144
  const int block = 256;
  const int grid = (total_threads + block - 1) / block;  // 1024
  embedding_gather_kernel<<<grid, block, 0, stream>>>(indices, W4, out4);
}

// Round 3
// 10.003 us; speedup vs baseline: 1.0049x; 1.0049x over previous
//
#include <hip/hip_runtime.h>
#include <hip/hip_bf16.h>

// Embedding gather: out[r, :] = W[indices[r], :], r in [0, 8192), D=128 f32.
// Unroll-2 per thread: prefetch both row indices (independent loads), then
// issue both W float4 gathers (independent), then nontemporal-store.
// Uses clang ext_vector float4 (native vector) so nontemporal builtins accept it.

typedef float f32x4 __attribute__((ext_vector_type(4)));

#define N_ROWS 8192           // 4 * 2048
#define DIM    128
#define F4_PER_ROW (DIM / 4)  // 32
#define TOTAL_F4 (N_ROWS * F4_PER_ROW)  // 262144
#define UNROLL 2
#define NTHREADS (TOTAL_F4 / UNROLL)    // 131072
#define BLOCK 256
#define GRID (NTHREADS / BLOCK)         // 512

__global__ __launch_bounds__(BLOCK) void embedding_gather_kernel(
    const int* __restrict__ indices,
    const f32x4* __restrict__ W4,
    f32x4* __restrict__ out4) {
  const int t = blockIdx.x * blockDim.x + threadIdx.x;  // [0, NTHREADS)

  int idxs[UNROLL];
#pragma unroll
  for (int k = 0; k < UNROLL; ++k) {
    const int row = (t + k * NTHREADS) >> 5;    // f4 index / 32 -> row
    idxs[k] = indices[row];                     // independent loads, both in flight
  }
  f32x4 vals[UNROLL];
#pragma unroll
  for (int k = 0; k < UNROLL; ++k) {
    const int f4 = t + k * NTHREADS;
    const int lane = f4 & 31;
    vals[k] = W4[(size_t)idxs[k] * F4_PER_ROW + lane];  // independent gathers
  }
#pragma unroll
  for (int k = 0; k < UNROLL; ++k) {
    const int f4 = t + k * NTHREADS;
    __builtin_nontemporal_store(vals[k], &out4[f4]);
  }
}

extern "C" void kernel_launch(void* const* d_in, const int* in_sizes, int n_in,
                              void* d_out, int out_size, void* d_ws, size_t ws_size,
                              hipStream_t stream) {
  const int* indices = (const int*)d_in[0];     // (4, 2048) int32
  const f32x4* W4    = (const f32x4*)d_in[1];   // (50257, 128) f32 as float4
  f32x4* out4        = (f32x4*)d_out;           // (4, 2048, 128) f32 as float4

  embedding_gather_kernel<<<GRID, BLOCK, 0, stream>>>(indices, W4, out4);
}